// Round 22
// baseline (256.201 us; speedup 1.0000x reference)
//
#include <hip/hip_runtime.h>
#include <hip/hip_bf16.h>
#include <math.h>

// ---------------------------------------------------------------------------
// DeepSeek MLHA. Round 22: global split-K attention. Grid 2048 =
// 32 streams x 32 q-groups x 2 key-halves (each half = G+1 tiles -> nt_max
// 66 -> 32, with 2x backfill pool). Blocks keep r19/21 internals; epilogue
// writes global partials (overlaid on dead ws buffers); combine kernel merges.
// GEMMs = round 18 (dbuf + fused + XCD swizzle).
// B=2, T=2048, hidden=2048, NH=16, NKV=4, HD=128, latent=256, kv_dim=512.
// ---------------------------------------------------------------------------

#define AS1 __attribute__((address_space(1)))
#define AS3 __attribute__((address_space(3)))
#define QSTRIDE 2304

typedef short bf16x8 __attribute__((ext_vector_type(8)));
typedef float f32x4 __attribute__((ext_vector_type(4)));
typedef float f32x16 __attribute__((ext_vector_type(16)));
typedef unsigned int uint32x2 __attribute__((ext_vector_type(2)));

__device__ __forceinline__ unsigned short f2bf(float x) {
  union { float f; unsigned int u; } q; q.f = x;
  unsigned int u = q.u;
  u += 0x7FFFu + ((u >> 16) & 1u);   // RNE
  return (unsigned short)(u >> 16);
}
__device__ __forceinline__ float bf2f(unsigned short x) {
  union { unsigned int u; float f; } q; q.u = ((unsigned int)x) << 16;
  return q.f;
}
__device__ __forceinline__ unsigned int pack2bf(float a, float b) {
  return (unsigned int)f2bf(a) | ((unsigned int)f2bf(b) << 16);
}
__device__ __forceinline__ unsigned int pack2bf_hw(float a, float b) {
  __hip_bfloat162 h = __float22bfloat162_rn(make_float2(a, b));
  union { __hip_bfloat162 h; unsigned int u; } c; c.h = h;
  return c.u;
}
__device__ __forceinline__ uint32x2 plswap(unsigned int a, unsigned int b) {
  return __builtin_amdgcn_permlane32_swap(a, b, false, false);
}
__device__ __forceinline__ float xor32_add(float x) {
  union { float f; unsigned int u; } X; X.f = x;
  uint32x2 r = plswap(X.u, X.u);
  union { unsigned int u; float f; } A, B; A.u = r.x; B.u = r.y;
  return A.f + B.f;
}

// --- RoPE cos/sin table ----------------------------------------------------
__global__ __launch_bounds__(256) void rope_table(float* __restrict__ cost,
                                                  float* __restrict__ sint,
                                                  int T) {
  int idx = blockIdx.x * 256 + threadIdx.x;
  if (idx >= T * 64) return;
  int t = idx >> 6, j = idx & 63;
  double invf = pow(10000.0, -(double)j / 64.0);
  double ang = (double)t * invf;
  cost[idx] = (float)cos(ang);
  sint[idx] = (float)sin(ang);
}

// --- fp32 -> bf16 convert --------------------------------------------------
__global__ __launch_bounds__(256) void conv_bf16(const float* __restrict__ src,
                                                 unsigned short* __restrict__ dst,
                                                 int n) {
  int i = (blockIdx.x * 256 + threadIdx.x) * 4;
  if (i >= n) return;
  float4 f = *(const float4*)(src + i);
  ushort4 o;
  o.x = f2bf(f.x); o.y = f2bf(f.y); o.z = f2bf(f.z); o.w = f2bf(f.w);
  *(ushort4*)(dst + i) = o;
}

// --- bf16 MFMA NT-GEMM, double-buffered prefetch + XCD-swizzled grid -------
template <bool OUT_BF16>
__global__ __launch_bounds__(256) void gemm_mfma(const unsigned short* __restrict__ A,
                                                 const unsigned short* __restrict__ W,
                                                 void* __restrict__ Cv,
                                                 int M, int N, int K,
                                                 int lda, int ldw, int ldc,
                                                 int nwgx) {
  __shared__ unsigned short Asl[2][128 * 32];
  __shared__ unsigned short Wsl[2][128 * 32];
  int tid = threadIdx.x;
  int w = tid >> 6, lane = tid & 63;
  int g = lane >> 4, c = lane & 15;
  int wm = w >> 1, wn = w & 1;

  int nwg = gridDim.x;
  int cpx = nwg >> 3;
  int orig = blockIdx.x;
  int swz = (orig & 7) * cpx + (orig >> 3);
  int m0 = (swz / nwgx) * 128, n0 = (swz % nwgx) * 128;

  f32x4 acc[4][4] = {};

#pragma unroll
  for (int i = 0; i < 2; ++i) {
    int idx = i * 256 + tid;
    int row = idx >> 2;
    int kk = (idx & 3) * 8;
    __builtin_amdgcn_global_load_lds(
        (const AS1 void*)(A + (size_t)(m0 + row) * lda + kk),
        (AS3 void*)(Asl[0] + ((size_t)i * 256 + (w << 6)) * 8), 16, 0, 0);
    __builtin_amdgcn_global_load_lds(
        (const AS1 void*)(W + (size_t)(n0 + row) * ldw + kk),
        (AS3 void*)(Wsl[0] + ((size_t)i * 256 + (w << 6)) * 8), 16, 0, 0);
  }
  __syncthreads();

  int cur = 0;
  for (int k0 = 0; k0 < K; k0 += 32) {
    if (k0 + 32 < K) {
      int nb = cur ^ 1;
#pragma unroll
      for (int i = 0; i < 2; ++i) {
        int idx = i * 256 + tid;
        int row = idx >> 2;
        int kk = (idx & 3) * 8;
        __builtin_amdgcn_global_load_lds(
            (const AS1 void*)(A + (size_t)(m0 + row) * lda + k0 + 32 + kk),
            (AS3 void*)(Asl[nb] + ((size_t)i * 256 + (w << 6)) * 8), 16, 0, 0);
        __builtin_amdgcn_global_load_lds(
            (const AS1 void*)(W + (size_t)(n0 + row) * ldw + k0 + 32 + kk),
            (AS3 void*)(Wsl[nb] + ((size_t)i * 256 + (w << 6)) * 8), 16, 0, 0);
      }
    }
    bf16x8 af[4], wf[4];
#pragma unroll
    for (int mi = 0; mi < 4; ++mi)
      af[mi] = *(const bf16x8*)(Asl[cur] + (wm * 64 + mi * 16 + c) * 32 + g * 8);
#pragma unroll
    for (int ni = 0; ni < 4; ++ni)
      wf[ni] = *(const bf16x8*)(Wsl[cur] + (wn * 64 + ni * 16 + c) * 32 + g * 8);
#pragma unroll
    for (int mi = 0; mi < 4; ++mi)
#pragma unroll
      for (int ni = 0; ni < 4; ++ni)
        acc[mi][ni] = __builtin_amdgcn_mfma_f32_16x16x32_bf16(af[mi], wf[ni],
                                                              acc[mi][ni], 0, 0, 0);
    __syncthreads();
    cur ^= 1;
  }
#pragma unroll
  for (int mi = 0; mi < 4; ++mi)
#pragma unroll
    for (int r = 0; r < 4; ++r) {
      size_t mrow = (size_t)(m0 + wm * 64 + mi * 16 + g * 4 + r) * ldc;
#pragma unroll
      for (int ni = 0; ni < 4; ++ni) {
        int n = n0 + wn * 64 + ni * 16 + c;
        if (OUT_BF16)
          ((unsigned short*)Cv)[mrow + n] = f2bf(acc[mi][ni][r]);
        else
          ((float*)Cv)[mrow + n] = acc[mi][ni][r];
      }
    }
}

// --- in-place RoPE on bf16 buffer with row stride --------------------------
__global__ __launch_bounds__(256) void rope_ip_bf16(unsigned short* __restrict__ buf,
                                                    int nheads, int T, int rowstride,
                                                    const float* __restrict__ cost,
                                                    const float* __restrict__ sint,
                                                    float scale) {
  int idx = blockIdx.x * 256 + threadIdx.x;
  int d = idx & 63;
  int rest = idx >> 6;
  int h = rest % nheads;
  int bt = rest / nheads;
  int t = bt & (T - 1);
  unsigned short* p = buf + (size_t)bt * rowstride + h * 128;
  float cc = cost[t * 64 + d], ss = sint[t * 64 + d];
  float x0 = bf2f(p[d]), x1 = bf2f(p[d + 64]);
  p[d]      = f2bf((x0 * cc - x1 * ss) * scale);
  p[d + 64] = f2bf((x1 * cc + x0 * ss) * scale);
}

// --- K: rope + pack into 32-key swizzled LDS-image tiles -------------------
__global__ __launch_bounds__(256) void rope_pack_k(const unsigned short* __restrict__ kvcat,
                                                   unsigned short* __restrict__ kp,
                                                   const float* __restrict__ cost,
                                                   const float* __restrict__ sint) {
  int idx = blockIdx.x * 256 + threadIdx.x;   // over B*T*4*64
  int d = idx & 63;
  int rest = idx >> 6;
  int kvh = rest & 3;
  int bt = rest >> 2;
  int t = bt & 2047, b = bt >> 11;
  const unsigned short* src = kvcat + (size_t)bt * 1024 + kvh * 128;
  float cc = cost[t * 64 + d], ss = sint[t * 64 + d];
  float x0 = bf2f(src[d]), x1 = bf2f(src[d + 64]);
  unsigned short y0 = f2bf(x0 * cc - x1 * ss);
  unsigned short y1 = f2bf(x1 * cc + x0 * ss);
  int kr = t & 31;
  size_t base = (size_t)(b * 4 + kvh) * 262144 + (size_t)(t >> 5) * 4096;
  kp[base + ((kr * 128 + d)      ^ ((kr & 7) << 3))] = y0;
  kp[base + ((kr * 128 + d + 64) ^ ((kr & 7) << 3))] = y1;
}

// --- V transpose -> 32-key swizzled LDS-image tiles ------------------------
__global__ __launch_bounds__(256) void transpose_v(const unsigned short* __restrict__ kvcat,
                                                   unsigned short* __restrict__ vp) {
  __shared__ unsigned short tile[32][33];
  int t0 = blockIdx.x * 32, d0 = blockIdx.y * 32, b = blockIdx.z;
  int tx = threadIdx.x & 31, ty = threadIdx.x >> 5;
#pragma unroll
  for (int i = 0; i < 4; ++i) {
    int t = ty + i * 8;
    tile[t][tx] = kvcat[((size_t)(b * 2048 + t0 + t)) * 1024 + 512 + d0 + tx];
  }
  __syncthreads();
#pragma unroll
  for (int i = 0; i < 4; ++i) {
    int dd = ty + i * 8;
    int D = d0 + dd;
    int d = D & 127;
    int t = t0 + tx;
    size_t base = (size_t)(b * 4 + (D >> 7)) * 262144 + (size_t)(t >> 5) * 4096;
    vp[base + ((d * 32 + (t & 31)) ^ ((d & 3) << 3))] = tile[tx][dd];
  }
}

// --- MFMA flash attention: global split-K halves ---------------------------
// bid: stream = bid&31; rest = bid>>5 (0..63); G = 31-(rest>>1); half=rest&1.
// Block computes q-group G (64 rows) over tiles [tstart,tend):
//   half 0: [0, G+1)   half 1: [G+1, 2G+2)   -- both G+1 tiles.
// Internals = r19/21 (2 q-subtiles x 2 k-parity warps, dbuf, LDS combine).
// Epilogue writes partial O (bf16, unscaled) + l (f32) to overlaid buffers.
__global__ __launch_bounds__(256, 2) void attn_mfma(const unsigned short* __restrict__ qb,
                                                    const unsigned short* __restrict__ kp,
                                                    const unsigned short* __restrict__ vp,
                                                    unsigned short* __restrict__ partA,
                                                    unsigned short* __restrict__ partB,
                                                    float* __restrict__ lpart) {
  // [0,4096) K0 | [4096,8192) K1 | [8192,12288) V0 | [12288,16384) V1
  // combine aliases [0,16384) as lO[2][64][128]; l at [16384,16896) as float[256]
  __shared__ unsigned short smem[16896];

  int tid = threadIdx.x;
  int w = tid >> 6, lane = tid & 63;
  int wq = w >> 1, wk = w & 1;
  int cl = lane & 31, hi = lane >> 5;
  int bid = blockIdx.x;
  int stream = bid & 31;
  int rest = bid >> 5;
  int G = 31 - (rest >> 1);           // longest q-groups first
  int half = rest & 1;
  int h = stream & 15, b = stream >> 4;
  int kvh = h >> 2;
  int q0w = G * 64 + wq * 32;
  int tstart = half ? (G + 1) : 0;
  int tend = half ? (2 * G + 2) : (G + 1);

  const unsigned short* kpS = kp + (size_t)(b * 4 + kvh) * 262144;
  const unsigned short* vpS = vp + (size_t)(b * 4 + kvh) * 262144;

  bf16x8 qa[8];
  {
    const unsigned short* qrow = qb + ((size_t)(b * 2048 + q0w + cl)) * QSTRIDE + h * 128 + hi * 8;
#pragma unroll
    for (int kc = 0; kc < 8; ++kc)
      qa[kc] = *(const bf16x8*)(qrow + kc * 16);
  }

  f32x16 o0 = {}, o1 = {}, o2 = {}, o3 = {};
  float l = 0.f;

  // ---- prologue: stage tile tstart into buf 0 ----
#pragma unroll
  for (int i = 0; i < 2; ++i) {
    size_t src = (size_t)tstart * 4096 + w * 1024 + i * 512 + lane * 8;
    __builtin_amdgcn_global_load_lds(
        (const AS1 void*)(kpS + src),
        (AS3 void*)(&smem[w * 1024 + i * 512]), 16, 0, 0);
    __builtin_amdgcn_global_load_lds(
        (const AS1 void*)(vpS + src),
        (AS3 void*)(&smem[8192 + w * 1024 + i * 512]), 16, 0, 0);
  }
  __syncthreads();

  int cur = 0;
  for (int ti = tstart; ti < tend; ++ti) {
    if (ti + 1 < tend) {
      size_t src = (size_t)(ti + 1) * 4096 + w * 1024 + lane * 8;
      int nb = cur ^ 1;
#pragma unroll
      for (int i = 0; i < 2; ++i) {
        __builtin_amdgcn_global_load_lds(
            (const AS1 void*)(kpS + src + i * 512),
            (AS3 void*)(&smem[nb * 4096 + w * 1024 + i * 512]), 16, 0, 0);
        __builtin_amdgcn_global_load_lds(
            (const AS1 void*)(vpS + src + i * 512),
            (AS3 void*)(&smem[8192 + nb * 4096 + w * 1024 + i * 512]), 16, 0, 0);
      }
    }
    int ks0 = ti << 5;
    if (((ti & 1) == wk) && (ks0 <= q0w)) {
      const unsigned short* kb_ = &smem[cur * 4096];
      const unsigned short* vb_ = &smem[8192 + cur * 4096];
      bf16x8 kf[8];
#pragma unroll
      for (int kc = 0; kc < 8; ++kc)
        kf[kc] = *(const bf16x8*)&kb_[(cl * 128 + kc * 16 + hi * 8) ^ ((cl & 7) << 3)];
      // QK^T: two independent 4-MFMA chains
      f32x16 sA = {}, sB = {};
      __builtin_amdgcn_s_setprio(1);
#pragma unroll
      for (int kc = 0; kc < 4; ++kc) {
        sA = __builtin_amdgcn_mfma_f32_32x32x16_bf16(kf[kc * 2],     qa[kc * 2],     sA, 0, 0, 0);
        sB = __builtin_amdgcn_mfma_f32_32x32x16_bf16(kf[kc * 2 + 1], qa[kc * 2 + 1], sB, 0, 0, 0);
      }
      __builtin_amdgcn_s_setprio(0);
      f32x16 sS = sA + sB;
      bf16x8 vf[8];
#pragma unroll
      for (int db = 0; db < 4; ++db)
#pragma unroll
        for (int ks = 0; ks < 2; ++ks)
          vf[db * 2 + ks] = *(const bf16x8*)&vb_[((db * 32 + cl) * 32
                              + ks * 16 + hi * 8) ^ ((cl & 3) << 3)];
      if (ks0 == q0w) {
#pragma unroll
        for (int r = 0; r < 16; ++r) {
          int krow = (r & 3) + 8 * (r >> 2) + 4 * hi;
          if (krow > cl) sS[r] = -INFINITY;
        }
      }
      float p[16];
#pragma unroll
      for (int r = 0; r < 16; ++r) p[r] = __expf(sS[r]);
      float rs = ((p[0] + p[1]) + (p[2] + p[3])) + ((p[4] + p[5]) + (p[6] + p[7]))
               + ((p[8] + p[9]) + (p[10] + p[11])) + ((p[12] + p[13]) + (p[14] + p[15]));
      l += rs;
      union { unsigned int u[4]; bf16x8 v; } pb0, pb1;
      {
        uint32x2 r0 = plswap(pack2bf_hw(p[0], p[1]), pack2bf_hw(p[4], p[5]));
        uint32x2 r1 = plswap(pack2bf_hw(p[2], p[3]), pack2bf_hw(p[6], p[7]));
        pb0.u[0] = r0.x; pb0.u[1] = r1.x; pb0.u[2] = r0.y; pb0.u[3] = r1.y;
        uint32x2 r2 = plswap(pack2bf_hw(p[8], p[9]), pack2bf_hw(p[12], p[13]));
        uint32x2 r3 = plswap(pack2bf_hw(p[10], p[11]), pack2bf_hw(p[14], p[15]));
        pb1.u[0] = r2.x; pb1.u[1] = r3.x; pb1.u[2] = r2.y; pb1.u[3] = r3.y;
      }
      __builtin_amdgcn_s_setprio(1);
      o0 = __builtin_amdgcn_mfma_f32_32x32x16_bf16(vf[0], pb0.v, o0, 0, 0, 0);
      o1 = __builtin_amdgcn_mfma_f32_32x32x16_bf16(vf[2], pb0.v, o1, 0, 0, 0);
      o2 = __builtin_amdgcn_mfma_f32_32x32x16_bf16(vf[4], pb0.v, o2, 0, 0, 0);
      o3 = __builtin_amdgcn_mfma_f32_32x32x16_bf16(vf[6], pb0.v, o3, 0, 0, 0);
      o0 = __builtin_amdgcn_mfma_f32_32x32x16_bf16(vf[1], pb1.v, o0, 0, 0, 0);
      o1 = __builtin_amdgcn_mfma_f32_32x32x16_bf16(vf[3], pb1.v, o1, 0, 0, 0);
      o2 = __builtin_amdgcn_mfma_f32_32x32x16_bf16(vf[5], pb1.v, o2, 0, 0, 0);
      o3 = __builtin_amdgcn_mfma_f32_32x32x16_bf16(vf[7], pb1.v, o3, 0, 0, 0);
      __builtin_amdgcn_s_setprio(0);
    }
    __syncthreads();
    cur ^= 1;
  }

  // ---- write per-warp partials into aliased LDS (parity combine) ----
  float lsum = xor32_add(l);
  float* lptr = (float*)&smem[16384];
  int qr = wq * 32 + cl;
  if (hi == 0) lptr[wk * 64 + qr] = lsum;
#pragma unroll
  for (int r = 0; r < 16; ++r) {
    int dl = (r & 3) + 8 * (r >> 2) + 4 * hi;
    smem[wk * 8192 + qr * 128 + dl]      = f2bf(o0[r]);
    smem[wk * 8192 + qr * 128 + 32 + dl] = f2bf(o1[r]);
    smem[wk * 8192 + qr * 128 + 64 + dl] = f2bf(o2[r]);
    smem[wk * 8192 + qr * 128 + 96 + dl] = f2bf(o3[r]);
  }
  __syncthreads();

  // ---- combine parities; write block partial to global (no normalize) ----
  {
    unsigned short* op = (bid < 1600) ? (partA + (size_t)bid * 8192)
                                      : (partB + (size_t)(bid - 1600) * 8192);
    int q = tid >> 2;
    int dc = (tid & 3) * 32;
    if ((tid & 3) == 0) lpart[(size_t)bid * 64 + q] = lptr[q] + lptr[64 + q];
#pragma unroll
    for (int i4 = 0; i4 < 4; ++i4) {
      bf16x8 a = *(const bf16x8*)&smem[q * 128 + dc + i4 * 8];
      bf16x8 c = *(const bf16x8*)&smem[8192 + q * 128 + dc + i4 * 8];
      union { unsigned int u[4]; bf16x8 v; } ov;
#pragma unroll
      for (int j = 0; j < 4; ++j) {
        float s0 = bf2f((unsigned short)a[j * 2])     + bf2f((unsigned short)c[j * 2]);
        float s1 = bf2f((unsigned short)a[j * 2 + 1]) + bf2f((unsigned short)c[j * 2 + 1]);
        ov.u[j] = pack2bf(s0, s1);
      }
      *(bf16x8*)(op + q * 128 + dc + i4 * 8) = ov.v;
    }
  }
}

// --- combine halves: attob = (P0 + P1) / (l0 + l1) -------------------------
// Grid 1024: id -> stream = id & 31, rest2 = id >> 5 (= 31 - G).
__global__ __launch_bounds__(256) void attn_combine(const unsigned short* __restrict__ partA,
                                                    const unsigned short* __restrict__ partB,
                                                    const float* __restrict__ lpart,
                                                    unsigned short* __restrict__ attob) {
  int id = blockIdx.x;
  int stream = id & 31;
  int rest2 = id >> 5;          // 0..31
  int G = 31 - rest2;
  int h = stream & 15, b = stream >> 4;
  int p0 = (2 * rest2) * 32 + stream;
  int p1 = p0 + 32;
  const unsigned short* o0 = (p0 < 1600) ? (partA + (size_t)p0 * 8192)
                                         : (partB + (size_t)(p0 - 1600) * 8192);
  const unsigned short* o1 = (p1 < 1600) ? (partA + (size_t)p1 * 8192)
                                         : (partB + (size_t)(p1 - 1600) * 8192);
  int tid = threadIdx.x;
  int q = tid >> 2;
  int dc = (tid & 3) * 32;
  float inv = 1.f / (lpart[(size_t)p0 * 64 + q] + lpart[(size_t)p1 * 64 + q]);
  unsigned short* orow = attob + ((size_t)(b * 2048 + G * 64 + q)) * 2048 + h * 128 + dc;
#pragma unroll
  for (int i4 = 0; i4 < 4; ++i4) {
    bf16x8 a = *(const bf16x8*)(o0 + q * 128 + dc + i4 * 8);
    bf16x8 c = *(const bf16x8*)(o1 + q * 128 + dc + i4 * 8);
    union { unsigned int u[4]; bf16x8 v; } ov;
#pragma unroll
    for (int j = 0; j < 4; ++j) {
      float s0 = (bf2f((unsigned short)a[j * 2])     + bf2f((unsigned short)c[j * 2]))     * inv;
      float s1 = (bf2f((unsigned short)a[j * 2 + 1]) + bf2f((unsigned short)c[j * 2 + 1])) * inv;
      ov.u[j] = pack2bf(s0, s1);
    }
    *(bf16x8*)(orow + i4 * 8) = ov.v;
  }
}

// ---------------------------------------------------------------------------
extern "C" void kernel_launch(void* const* d_in, const int* in_sizes, int n_in,
                              void* d_out, int out_size, void* d_ws, size_t ws_size,
                              hipStream_t stream) {
  const float* x   = (const float*)d_in[0];
  const float* wq  = (const float*)d_in[1];
  const float* wkv = (const float*)d_in[2];
  const float* wk  = (const float*)d_in[3];
  const float* wv  = (const float*)d_in[4];
  const float* wo  = (const float*)d_in[5];
  float* out = (float*)d_out;
  float* ws  = (float*)d_ws;

  const int B = 2, T = 2048, H = 2048, NH = 16, NKV = 4, LAT = 256, KVD = 512;
  const int BT = B * T;  // 4096

  size_t off = 0;
  unsigned short* xb    = (unsigned short*)(ws + off); off += (size_t)BT * H / 2;
  unsigned short* wqb   = (unsigned short*)(ws + off); off += (size_t)H * H / 2;     // } adjacent:
  unsigned short* wkvb  = (unsigned short*)(ws + off); off += (size_t)LAT * H / 2;   // } W' 2304x2048
  unsigned short* wkb   = (unsigned short*)(ws + off); off += (size_t)KVD * LAT / 2; // } adjacent:
  unsigned short* wvb   = (unsigned short*)(ws + off); off += (size_t)KVD * LAT / 2; // } W'' 1024x256
  unsigned short* wob   = (unsigned short*)(ws + off); off += (size_t)H * H / 2;
  unsigned short* qkv   = (unsigned short*)(ws + off); off += (size_t)BT * QSTRIDE / 2;
  unsigned short* kvcat = (unsigned short*)(ws + off); off += (size_t)BT * 1024 / 2;
  unsigned short* kp    = (unsigned short*)(ws + off); off += (size_t)BT * KVD / 2;
  unsigned short* vp    = (unsigned short*)(ws + off); off += (size_t)BT * KVD / 2;
  unsigned short* attob = (unsigned short*)(ws + off); off += (size_t)BT * H / 2;
  float* cost = ws + off; off += (size_t)T * 64;
  float* sint = ws + off; off += (size_t)T * 64;

  // Split-K partial overlays (dead regions during/after attention):
  //  partA over xb..wvb (26.74 MB >= 1600 x 16 KB = 26.2 MB)
  //  partB over kvcat (8.39 MB >= 448 x 16 KB + 2048*64*4 B = 7.86 MB)
  unsigned short* partA = (unsigned short*)ws;
  unsigned short* partB = kvcat;
  float* lpart = (float*)(kvcat + (size_t)448 * 8192);

  const float scale = 0.088388347648318447f;  // 1/sqrt(128)

  rope_table<<<(T * 64 + 255) / 256, 256, 0, stream>>>(cost, sint, T);

  conv_bf16<<<(BT * H / 4) / 256, 256, 0, stream>>>(x, xb, BT * H);
  conv_bf16<<<(H * H / 4) / 256, 256, 0, stream>>>(wq, wqb, H * H);
  conv_bf16<<<(LAT * H / 4) / 256, 256, 0, stream>>>(wkv, wkvb, LAT * H);
  conv_bf16<<<(KVD * LAT / 4) / 256, 256, 0, stream>>>(wk, wkb, KVD * LAT);
  conv_bf16<<<(KVD * LAT / 4) / 256, 256, 0, stream>>>(wv, wvb, KVD * LAT);
  conv_bf16<<<(H * H / 4) / 256, 256, 0, stream>>>(wo, wob, H * H);

  // Fused q + kv-latent projection: W' = [wq; wkv] (2304x2048), grid 576 (%8==0)
  gemm_mfma<true><<<(QSTRIDE / 128) * (BT / 128), 256, 0, stream>>>(
      xb, wqb, qkv, BT, QSTRIDE, H, H, H, QSTRIDE, QSTRIDE / 128);
  // Fused k + v projection: W'' (1024x256), grid 256 (%8==0)
  gemm_mfma<true><<<(1024 / 128) * (BT / 128), 256, 0, stream>>>(
      qkv + H, wkb, kvcat, BT, 1024, LAT, QSTRIDE, LAT, 1024, 1024 / 128);

  // Q: rope in place (scale folded). K: rope + pack. V: transpose + pack.
  rope_ip_bf16<<<(BT * NH * 64) / 256, 256, 0, stream>>>(qkv, NH, T, QSTRIDE, cost, sint, scale);
  rope_pack_k<<<(BT * NKV * 64) / 256, 256, 0, stream>>>(kvcat, kp, cost, sint);
  transpose_v<<<dim3(T / 32, KVD / 32, B), 256, 0, stream>>>(kvcat, vp);

  // Attention: 2048 split-K blocks (32 streams x 32 G x 2 halves), 4 warps
  attn_mfma<<<2048, 256, 0, stream>>>(qkv, kp, vp, partA, partB, lpart);
  // Merge the two key-halves and normalize
  attn_combine<<<1024, 256, 0, stream>>>(partA, partB, lpart, attob);

  // Output projection: grid 512 (%8==0)
  gemm_mfma<false><<<(H / 128) * (BT / 128), 256, 0, stream>>>(
      attob, wob, out, BT, H, H, H, H, H, H / 128);
}

// Round 23
// 214.992 us; speedup vs baseline: 1.1917x; 1.1917x over previous
//
#include <hip/hip_runtime.h>
#include <hip/hip_bf16.h>
#include <math.h>

// ---------------------------------------------------------------------------
// DeepSeek MLHA. Round 23: revert attention to round-21 (74.9us verified;
// r22 split-K regressed). Fuse the 6 fp32->bf16 weight/activation converts
// into one grid-strided kernel (fewer launches/gaps).
// GEMMs = round 18 (dbuf + fused projections + XCD swizzle).
// B=2, T=2048, hidden=2048, NH=16, NKV=4, HD=128, latent=256, kv_dim=512.
// ---------------------------------------------------------------------------

#define AS1 __attribute__((address_space(1)))
#define AS3 __attribute__((address_space(3)))
#define QSTRIDE 2304

typedef short bf16x8 __attribute__((ext_vector_type(8)));
typedef float f32x4 __attribute__((ext_vector_type(4)));
typedef float f32x16 __attribute__((ext_vector_type(16)));
typedef unsigned int uint32x2 __attribute__((ext_vector_type(2)));

__device__ __forceinline__ unsigned short f2bf(float x) {
  union { float f; unsigned int u; } q; q.f = x;
  unsigned int u = q.u;
  u += 0x7FFFu + ((u >> 16) & 1u);   // RNE
  return (unsigned short)(u >> 16);
}
__device__ __forceinline__ float bf2f(unsigned short x) {
  union { unsigned int u; float f; } q; q.u = ((unsigned int)x) << 16;
  return q.f;
}
__device__ __forceinline__ unsigned int pack2bf(float a, float b) {
  return (unsigned int)f2bf(a) | ((unsigned int)f2bf(b) << 16);
}
__device__ __forceinline__ unsigned int pack2bf_hw(float a, float b) {
  __hip_bfloat162 h = __float22bfloat162_rn(make_float2(a, b));
  union { __hip_bfloat162 h; unsigned int u; } c; c.h = h;
  return c.u;
}
__device__ __forceinline__ uint32x2 plswap(unsigned int a, unsigned int b) {
  return __builtin_amdgcn_permlane32_swap(a, b, false, false);
}
__device__ __forceinline__ float xor32_add(float x) {
  union { float f; unsigned int u; } X; X.f = x;
  uint32x2 r = plswap(X.u, X.u);
  union { unsigned int u; float f; } A, B; A.u = r.x; B.u = r.y;
  return A.f + B.f;
}

// --- RoPE cos/sin table ----------------------------------------------------
__global__ __launch_bounds__(256) void rope_table(float* __restrict__ cost,
                                                  float* __restrict__ sint,
                                                  int T) {
  int idx = blockIdx.x * 256 + threadIdx.x;
  if (idx >= T * 64) return;
  int t = idx >> 6, j = idx & 63;
  double invf = pow(10000.0, -(double)j / 64.0);
  double ang = (double)t * invf;
  cost[idx] = (float)cos(ang);
  sint[idx] = (float)sin(ang);
}

// --- fused fp32 -> bf16 converts: all 6 tensors in one launch --------------
// dst is the contiguous ws region [xb .. wob); source chosen by flat range.
__global__ __launch_bounds__(256) void conv_all(const float* __restrict__ x,
                                                const float* __restrict__ wq,
                                                const float* __restrict__ wkv,
                                                const float* __restrict__ wk,
                                                const float* __restrict__ wv,
                                                const float* __restrict__ wo,
                                                unsigned short* __restrict__ dst) {
  const int b0 = 8388608;            // x        (B*T*H)
  const int b1 = b0 + 4194304;       // wq       (H*H)
  const int b2 = b1 + 524288;        // wkv      (LAT*H)
  const int b3 = b2 + 131072;        // wk       (KVD*LAT)
  const int b4 = b3 + 131072;        // wv       (KVD*LAT)
  const int b5 = b4 + 4194304;       // wo       (H*H)
  int i = (blockIdx.x * 256 + threadIdx.x) * 4;
  if (i >= b5) return;
  const float* src;
  int off;
  if (i < b0)      { src = x;   off = i; }
  else if (i < b1) { src = wq;  off = i - b0; }
  else if (i < b2) { src = wkv; off = i - b1; }
  else if (i < b3) { src = wk;  off = i - b2; }
  else if (i < b4) { src = wv;  off = i - b3; }
  else             { src = wo;  off = i - b4; }
  float4 f = *(const float4*)(src + off);
  ushort4 o;
  o.x = f2bf(f.x); o.y = f2bf(f.y); o.z = f2bf(f.z); o.w = f2bf(f.w);
  *(ushort4*)(dst + i) = o;
}

// --- bf16 MFMA NT-GEMM, double-buffered prefetch + XCD-swizzled grid -------
template <bool OUT_BF16>
__global__ __launch_bounds__(256) void gemm_mfma(const unsigned short* __restrict__ A,
                                                 const unsigned short* __restrict__ W,
                                                 void* __restrict__ Cv,
                                                 int M, int N, int K,
                                                 int lda, int ldw, int ldc,
                                                 int nwgx) {
  __shared__ unsigned short Asl[2][128 * 32];
  __shared__ unsigned short Wsl[2][128 * 32];
  int tid = threadIdx.x;
  int w = tid >> 6, lane = tid & 63;
  int g = lane >> 4, c = lane & 15;
  int wm = w >> 1, wn = w & 1;

  int nwg = gridDim.x;
  int cpx = nwg >> 3;
  int orig = blockIdx.x;
  int swz = (orig & 7) * cpx + (orig >> 3);
  int m0 = (swz / nwgx) * 128, n0 = (swz % nwgx) * 128;

  f32x4 acc[4][4] = {};

#pragma unroll
  for (int i = 0; i < 2; ++i) {
    int idx = i * 256 + tid;
    int row = idx >> 2;
    int kk = (idx & 3) * 8;
    __builtin_amdgcn_global_load_lds(
        (const AS1 void*)(A + (size_t)(m0 + row) * lda + kk),
        (AS3 void*)(Asl[0] + ((size_t)i * 256 + (w << 6)) * 8), 16, 0, 0);
    __builtin_amdgcn_global_load_lds(
        (const AS1 void*)(W + (size_t)(n0 + row) * ldw + kk),
        (AS3 void*)(Wsl[0] + ((size_t)i * 256 + (w << 6)) * 8), 16, 0, 0);
  }
  __syncthreads();

  int cur = 0;
  for (int k0 = 0; k0 < K; k0 += 32) {
    if (k0 + 32 < K) {
      int nb = cur ^ 1;
#pragma unroll
      for (int i = 0; i < 2; ++i) {
        int idx = i * 256 + tid;
        int row = idx >> 2;
        int kk = (idx & 3) * 8;
        __builtin_amdgcn_global_load_lds(
            (const AS1 void*)(A + (size_t)(m0 + row) * lda + k0 + 32 + kk),
            (AS3 void*)(Asl[nb] + ((size_t)i * 256 + (w << 6)) * 8), 16, 0, 0);
        __builtin_amdgcn_global_load_lds(
            (const AS1 void*)(W + (size_t)(n0 + row) * ldw + k0 + 32 + kk),
            (AS3 void*)(Wsl[nb] + ((size_t)i * 256 + (w << 6)) * 8), 16, 0, 0);
      }
    }
    bf16x8 af[4], wf[4];
#pragma unroll
    for (int mi = 0; mi < 4; ++mi)
      af[mi] = *(const bf16x8*)(Asl[cur] + (wm * 64 + mi * 16 + c) * 32 + g * 8);
#pragma unroll
    for (int ni = 0; ni < 4; ++ni)
      wf[ni] = *(const bf16x8*)(Wsl[cur] + (wn * 64 + ni * 16 + c) * 32 + g * 8);
#pragma unroll
    for (int mi = 0; mi < 4; ++mi)
#pragma unroll
      for (int ni = 0; ni < 4; ++ni)
        acc[mi][ni] = __builtin_amdgcn_mfma_f32_16x16x32_bf16(af[mi], wf[ni],
                                                              acc[mi][ni], 0, 0, 0);
    __syncthreads();
    cur ^= 1;
  }
#pragma unroll
  for (int mi = 0; mi < 4; ++mi)
#pragma unroll
    for (int r = 0; r < 4; ++r) {
      size_t mrow = (size_t)(m0 + wm * 64 + mi * 16 + g * 4 + r) * ldc;
#pragma unroll
      for (int ni = 0; ni < 4; ++ni) {
        int n = n0 + wn * 64 + ni * 16 + c;
        if (OUT_BF16)
          ((unsigned short*)Cv)[mrow + n] = f2bf(acc[mi][ni][r]);
        else
          ((float*)Cv)[mrow + n] = acc[mi][ni][r];
      }
    }
}

// --- in-place RoPE on bf16 buffer with row stride --------------------------
__global__ __launch_bounds__(256) void rope_ip_bf16(unsigned short* __restrict__ buf,
                                                    int nheads, int T, int rowstride,
                                                    const float* __restrict__ cost,
                                                    const float* __restrict__ sint,
                                                    float scale) {
  int idx = blockIdx.x * 256 + threadIdx.x;
  int d = idx & 63;
  int rest = idx >> 6;
  int h = rest % nheads;
  int bt = rest / nheads;
  int t = bt & (T - 1);
  unsigned short* p = buf + (size_t)bt * rowstride + h * 128;
  float cc = cost[t * 64 + d], ss = sint[t * 64 + d];
  float x0 = bf2f(p[d]), x1 = bf2f(p[d + 64]);
  p[d]      = f2bf((x0 * cc - x1 * ss) * scale);
  p[d + 64] = f2bf((x1 * cc + x0 * ss) * scale);
}

// --- K: rope + pack into 32-key swizzled LDS-image tiles -------------------
__global__ __launch_bounds__(256) void rope_pack_k(const unsigned short* __restrict__ kvcat,
                                                   unsigned short* __restrict__ kp,
                                                   const float* __restrict__ cost,
                                                   const float* __restrict__ sint) {
  int idx = blockIdx.x * 256 + threadIdx.x;   // over B*T*4*64
  int d = idx & 63;
  int rest = idx >> 6;
  int kvh = rest & 3;
  int bt = rest >> 2;
  int t = bt & 2047, b = bt >> 11;
  const unsigned short* src = kvcat + (size_t)bt * 1024 + kvh * 128;
  float cc = cost[t * 64 + d], ss = sint[t * 64 + d];
  float x0 = bf2f(src[d]), x1 = bf2f(src[d + 64]);
  unsigned short y0 = f2bf(x0 * cc - x1 * ss);
  unsigned short y1 = f2bf(x1 * cc + x0 * ss);
  int kr = t & 31;
  size_t base = (size_t)(b * 4 + kvh) * 262144 + (size_t)(t >> 5) * 4096;
  kp[base + ((kr * 128 + d)      ^ ((kr & 7) << 3))] = y0;
  kp[base + ((kr * 128 + d + 64) ^ ((kr & 7) << 3))] = y1;
}

// --- V transpose -> 32-key swizzled LDS-image tiles ------------------------
__global__ __launch_bounds__(256) void transpose_v(const unsigned short* __restrict__ kvcat,
                                                   unsigned short* __restrict__ vp) {
  __shared__ unsigned short tile[32][33];
  int t0 = blockIdx.x * 32, d0 = blockIdx.y * 32, b = blockIdx.z;
  int tx = threadIdx.x & 31, ty = threadIdx.x >> 5;
#pragma unroll
  for (int i = 0; i < 4; ++i) {
    int t = ty + i * 8;
    tile[t][tx] = kvcat[((size_t)(b * 2048 + t0 + t)) * 1024 + 512 + d0 + tx];
  }
  __syncthreads();
#pragma unroll
  for (int i = 0; i < 4; ++i) {
    int dd = ty + i * 8;
    int D = d0 + dd;
    int d = D & 127;
    int t = t0 + tx;
    size_t base = (size_t)(b * 4 + (D >> 7)) * 262144 + (size_t)(t >> 5) * 4096;
    vp[base + ((d * 32 + (t & 31)) ^ ((d & 3) << 3))] = tile[tx][dd];
  }
}

// --- MFMA flash attention (round-21 verified, 74.9us) ----------------------
// Block = 2 q-tiles x 2 k-parity warps over q [G*64, G*64+64), KVBLK=32,
// dbuf LDS, split QK chains, hw packed cvt, LDS parity-combine.
__global__ __launch_bounds__(256, 2) void attn_mfma(const unsigned short* __restrict__ qb,
                                                    const unsigned short* __restrict__ kp,
                                                    const unsigned short* __restrict__ vp,
                                                    unsigned short* __restrict__ attob) {
  __shared__ unsigned short smem[16896];

  int tid = threadIdx.x;
  int w = tid >> 6, lane = tid & 63;
  int wq = w >> 1, wk = w & 1;
  int cl = lane & 31, hi = lane >> 5;
  int stream = blockIdx.x & 31;
  int G = 31 - (blockIdx.x >> 5);     // longest q-groups first
  int h = stream & 15, b = stream >> 4;
  int kvh = h >> 2;
  int q0w = G * 64 + wq * 32;
  int nt = 2 * G + 2;

  const unsigned short* kpS = kp + (size_t)(b * 4 + kvh) * 262144;
  const unsigned short* vpS = vp + (size_t)(b * 4 + kvh) * 262144;

  bf16x8 qa[8];
  {
    const unsigned short* qrow = qb + ((size_t)(b * 2048 + q0w + cl)) * QSTRIDE + h * 128 + hi * 8;
#pragma unroll
    for (int kc = 0; kc < 8; ++kc)
      qa[kc] = *(const bf16x8*)(qrow + kc * 16);
  }

  f32x16 o0 = {}, o1 = {}, o2 = {}, o3 = {};
  float l = 0.f;

#pragma unroll
  for (int i = 0; i < 2; ++i) {
    __builtin_amdgcn_global_load_lds(
        (const AS1 void*)(kpS + (size_t)w * 1024 + i * 512 + lane * 8),
        (AS3 void*)(&smem[w * 1024 + i * 512]), 16, 0, 0);
    __builtin_amdgcn_global_load_lds(
        (const AS1 void*)(vpS + (size_t)w * 1024 + i * 512 + lane * 8),
        (AS3 void*)(&smem[8192 + w * 1024 + i * 512]), 16, 0, 0);
  }
  __syncthreads();

  int cur = 0;
  for (int ti = 0; ti < nt; ++ti) {
    if (ti + 1 < nt) {
      size_t src = (size_t)(ti + 1) * 4096 + w * 1024 + lane * 8;
      int nb = cur ^ 1;
#pragma unroll
      for (int i = 0; i < 2; ++i) {
        __builtin_amdgcn_global_load_lds(
            (const AS1 void*)(kpS + src + i * 512),
            (AS3 void*)(&smem[nb * 4096 + w * 1024 + i * 512]), 16, 0, 0);
        __builtin_amdgcn_global_load_lds(
            (const AS1 void*)(vpS + src + i * 512),
            (AS3 void*)(&smem[8192 + nb * 4096 + w * 1024 + i * 512]), 16, 0, 0);
      }
    }
    int ks0 = ti << 5;
    if (((ti & 1) == wk) && (ks0 <= q0w)) {
      const unsigned short* kb_ = &smem[cur * 4096];
      const unsigned short* vb_ = &smem[8192 + cur * 4096];
      bf16x8 kf[8];
#pragma unroll
      for (int kc = 0; kc < 8; ++kc)
        kf[kc] = *(const bf16x8*)&kb_[(cl * 128 + kc * 16 + hi * 8) ^ ((cl & 7) << 3)];
      f32x16 sA = {}, sB = {};
      __builtin_amdgcn_s_setprio(1);
#pragma unroll
      for (int kc = 0; kc < 4; ++kc) {
        sA = __builtin_amdgcn_mfma_f32_32x32x16_bf16(kf[kc * 2],     qa[kc * 2],     sA, 0, 0, 0);
        sB = __builtin_amdgcn_mfma_f32_32x32x16_bf16(kf[kc * 2 + 1], qa[kc * 2 + 1], sB, 0, 0, 0);
      }
      __builtin_amdgcn_s_setprio(0);
      f32x16 sS = sA + sB;
      bf16x8 vf[8];
#pragma unroll
      for (int db = 0; db < 4; ++db)
#pragma unroll
        for (int ks = 0; ks < 2; ++ks)
          vf[db * 2 + ks] = *(const bf16x8*)&vb_[((db * 32 + cl) * 32
                              + ks * 16 + hi * 8) ^ ((cl & 3) << 3)];
      if (ks0 == q0w) {
#pragma unroll
        for (int r = 0; r < 16; ++r) {
          int krow = (r & 3) + 8 * (r >> 2) + 4 * hi;
          if (krow > cl) sS[r] = -INFINITY;
        }
      }
      float p[16];
#pragma unroll
      for (int r = 0; r < 16; ++r) p[r] = __expf(sS[r]);
      float rs = ((p[0] + p[1]) + (p[2] + p[3])) + ((p[4] + p[5]) + (p[6] + p[7]))
               + ((p[8] + p[9]) + (p[10] + p[11])) + ((p[12] + p[13]) + (p[14] + p[15]));
      l += rs;
      union { unsigned int u[4]; bf16x8 v; } pb0, pb1;
      {
        uint32x2 r0 = plswap(pack2bf_hw(p[0], p[1]), pack2bf_hw(p[4], p[5]));
        uint32x2 r1 = plswap(pack2bf_hw(p[2], p[3]), pack2bf_hw(p[6], p[7]));
        pb0.u[0] = r0.x; pb0.u[1] = r1.x; pb0.u[2] = r0.y; pb0.u[3] = r1.y;
        uint32x2 r2 = plswap(pack2bf_hw(p[8], p[9]), pack2bf_hw(p[12], p[13]));
        uint32x2 r3 = plswap(pack2bf_hw(p[10], p[11]), pack2bf_hw(p[14], p[15]));
        pb1.u[0] = r2.x; pb1.u[1] = r3.x; pb1.u[2] = r2.y; pb1.u[3] = r3.y;
      }
      __builtin_amdgcn_s_setprio(1);
      o0 = __builtin_amdgcn_mfma_f32_32x32x16_bf16(vf[0], pb0.v, o0, 0, 0, 0);
      o1 = __builtin_amdgcn_mfma_f32_32x32x16_bf16(vf[2], pb0.v, o1, 0, 0, 0);
      o2 = __builtin_amdgcn_mfma_f32_32x32x16_bf16(vf[4], pb0.v, o2, 0, 0, 0);
      o3 = __builtin_amdgcn_mfma_f32_32x32x16_bf16(vf[6], pb0.v, o3, 0, 0, 0);
      o0 = __builtin_amdgcn_mfma_f32_32x32x16_bf16(vf[1], pb1.v, o0, 0, 0, 0);
      o1 = __builtin_amdgcn_mfma_f32_32x32x16_bf16(vf[3], pb1.v, o1, 0, 0, 0);
      o2 = __builtin_amdgcn_mfma_f32_32x32x16_bf16(vf[5], pb1.v, o2, 0, 0, 0);
      o3 = __builtin_amdgcn_mfma_f32_32x32x16_bf16(vf[7], pb1.v, o3, 0, 0, 0);
      __builtin_amdgcn_s_setprio(0);
    }
    __syncthreads();
    cur ^= 1;
  }

  float lsum = xor32_add(l);
  float* lptr = (float*)&smem[16384];
  int qr = wq * 32 + cl;
  if (hi == 0) lptr[wk * 64 + qr] = lsum;
#pragma unroll
  for (int r = 0; r < 16; ++r) {
    int dl = (r & 3) + 8 * (r >> 2) + 4 * hi;
    smem[wk * 8192 + qr * 128 + dl]      = f2bf(o0[r]);
    smem[wk * 8192 + qr * 128 + 32 + dl] = f2bf(o1[r]);
    smem[wk * 8192 + qr * 128 + 64 + dl] = f2bf(o2[r]);
    smem[wk * 8192 + qr * 128 + 96 + dl] = f2bf(o3[r]);
  }
  __syncthreads();

  {
    int q = tid >> 2;
    int dc = (tid & 3) * 32;
    float inv = 1.f / (lptr[q] + lptr[64 + q]);
    unsigned short* orow = attob + ((size_t)(b * 2048 + G * 64 + q)) * 2048 + h * 128 + dc;
#pragma unroll
    for (int i4 = 0; i4 < 4; ++i4) {
      bf16x8 a = *(const bf16x8*)&smem[q * 128 + dc + i4 * 8];
      bf16x8 c = *(const bf16x8*)&smem[8192 + q * 128 + dc + i4 * 8];
      union { unsigned int u[4]; bf16x8 v; } ov;
#pragma unroll
      for (int j = 0; j < 4; ++j) {
        float s0 = (bf2f((unsigned short)a[j * 2])     + bf2f((unsigned short)c[j * 2]))     * inv;
        float s1 = (bf2f((unsigned short)a[j * 2 + 1]) + bf2f((unsigned short)c[j * 2 + 1])) * inv;
        ov.u[j] = pack2bf(s0, s1);
      }
      *(bf16x8*)(orow + i4 * 8) = ov.v;
    }
  }
}

// ---------------------------------------------------------------------------
extern "C" void kernel_launch(void* const* d_in, const int* in_sizes, int n_in,
                              void* d_out, int out_size, void* d_ws, size_t ws_size,
                              hipStream_t stream) {
  const float* x   = (const float*)d_in[0];
  const float* wq  = (const float*)d_in[1];
  const float* wkv = (const float*)d_in[2];
  const float* wk  = (const float*)d_in[3];
  const float* wv  = (const float*)d_in[4];
  const float* wo  = (const float*)d_in[5];
  float* out = (float*)d_out;
  float* ws  = (float*)d_ws;

  const int B = 2, T = 2048, H = 2048, NH = 16, NKV = 4, LAT = 256, KVD = 512;
  const int BT = B * T;  // 4096

  size_t off = 0;
  unsigned short* xb    = (unsigned short*)(ws + off); off += (size_t)BT * H / 2;
  unsigned short* wqb   = (unsigned short*)(ws + off); off += (size_t)H * H / 2;     // } adjacent:
  unsigned short* wkvb  = (unsigned short*)(ws + off); off += (size_t)LAT * H / 2;   // } W' 2304x2048
  unsigned short* wkb   = (unsigned short*)(ws + off); off += (size_t)KVD * LAT / 2; // } adjacent:
  unsigned short* wvb   = (unsigned short*)(ws + off); off += (size_t)KVD * LAT / 2; // } W'' 1024x256
  unsigned short* wob   = (unsigned short*)(ws + off); off += (size_t)H * H / 2;
  unsigned short* qkv   = (unsigned short*)(ws + off); off += (size_t)BT * QSTRIDE / 2;
  unsigned short* kvcat = (unsigned short*)(ws + off); off += (size_t)BT * 1024 / 2;
  unsigned short* kp    = (unsigned short*)(ws + off); off += (size_t)BT * KVD / 2;
  unsigned short* vp    = (unsigned short*)(ws + off); off += (size_t)BT * KVD / 2;
  unsigned short* attob = (unsigned short*)(ws + off); off += (size_t)BT * H / 2;
  float* cost = ws + off; off += (size_t)T * 64;
  float* sint = ws + off; off += (size_t)T * 64;

  const float scale = 0.088388347648318447f;  // 1/sqrt(128)

  rope_table<<<(T * 64 + 255) / 256, 256, 0, stream>>>(cost, sint, T);

  // All fp32->bf16 converts in one launch (17563648 elems / 4 / 256 = 17152)
  conv_all<<<17152, 256, 0, stream>>>(x, wq, wkv, wk, wv, wo, xb);

  // Fused q + kv-latent projection: W' = [wq; wkv] (2304x2048), grid 576 (%8==0)
  gemm_mfma<true><<<(QSTRIDE / 128) * (BT / 128), 256, 0, stream>>>(
      xb, wqb, qkv, BT, QSTRIDE, H, H, H, QSTRIDE, QSTRIDE / 128);
  // Fused k + v projection: W'' (1024x256), grid 256 (%8==0)
  gemm_mfma<true><<<(1024 / 128) * (BT / 128), 256, 0, stream>>>(
      qkv + H, wkb, kvcat, BT, 1024, LAT, QSTRIDE, LAT, 1024, 1024 / 128);

  // Q: rope in place (scale folded). K: rope + pack. V: transpose + pack.
  rope_ip_bf16<<<(BT * NH * 64) / 256, 256, 0, stream>>>(qkv, NH, T, QSTRIDE, cost, sint, scale);
  rope_pack_k<<<(BT * NKV * 64) / 256, 256, 0, stream>>>(kvcat, kp, cost, sint);
  transpose_v<<<dim3(T / 32, KVD / 32, B), 256, 0, stream>>>(kvcat, vp);

  // Attention: 1024 blocks = 32 streams x 32 q-groups (64 q each), 4 warps
  attn_mfma<<<1024, 256, 0, stream>>>(qkv, kp, vp, attob);

  // Output projection: grid 512 (%8==0)
  gemm_mfma<false><<<(H / 128) * (BT / 128), 256, 0, stream>>>(
      attob, wob, out, BT, H, H, H, H, H, H / 128);
}